// Round 1
// baseline (369.271 us; speedup 1.0000x reference)
//
#include <hip/hip_runtime.h>

namespace {

constexpr int kB = 256;
constexpr int kT = 1024;
constexpr int kC = 64;

// One wave (64 lanes) per batch chain. lane = class j.
// Linear-domain forward recursion:
//   p_t[j] = (sum_i p_{t-1}[i] * W[i][j]) * exp(x'_t[j]),  W = exp(U)
// with max-renormalization every 8 steps (log carried in logacc).
// Path energy (emission + transition along gold path) fused into same loop.
__global__ __launch_bounds__(64, 1) void crf_fwd(
    const float* __restrict__ x,    // [B,T,C]
    const float* __restrict__ U,    // [C,C]
    const float* __restrict__ bs,   // [C]
    const float* __restrict__ be,   // [C]
    const int*   __restrict__ y,    // [B,T]
    float*       __restrict__ out)  // [B,1]
{
  const int b = blockIdx.x;
  const int j = threadIdx.x & 63;

  __shared__ __align__(16) float pbuf[kC];

  const float* xrow = x + (size_t)b * kT * kC + j;  // stride kC per step
  const int*   yrow = y + (size_t)b * kT;

  // W column for this lane: Wcol[i] = exp(U[i][j])  (64 VGPRs)
  float Wcol[kC];
#pragma unroll
  for (int i = 0; i < kC; ++i) Wcol[i] = __expf(U[i * kC + j]);

  const float bsj = bs[j];
  const float bej = be[j];

  // preload group 0 (t = 0..7)
  float xb[8];
  int   yb[8];
#pragma unroll
  for (int k = 0; k < 8; ++k) {
    xb[k] = xrow[k * kC];
    yb[k] = yrow[k];
  }

  // ---- t = 0 init ----
  const float x0 = xb[0] + bsj;        // boundary-boosted emission at t=0
  float p = __expf(x0);                // alpha_0 in linear domain
  float emit   = (j == yb[0]) ? x0 : 0.f;
  float trans  = 0.f;                  // uniform across lanes
  float logacc = 0.f;                  // uniform across lanes
  int   yprev  = yb[0];
  pbuf[j] = p;

  // ---- main loop: 128 groups of 8 steps ----
  for (int g = 0; g < 128; ++g) {
    float xn[8];
    int   yn[8];
    const bool more = (g < 127);
    if (more) {
      // prefetch next group's x/y one group (~8 steps) ahead of use
#pragma unroll
      for (int k = 0; k < 8; ++k) {
        xn[k] = xrow[((g + 1) * 8 + k) * kC];
        yn[k] = yrow[(g + 1) * 8 + k];
      }
    }

#pragma unroll
    for (int k = 0; k < 8; ++k) {
      if (k == 0 && g == 0) continue;  // t=0 handled in init
      float xe = xb[k];
      if (k == 7 && g == 127) xe += bej;  // t == T-1 boundary
      const int yt = yb[k];

      // path energy terms
      emit  += (j == yt) ? xe : 0.f;
      trans += U[yprev * kC + yt];   // uniform scalar gather (L1-hot, 16 KB)
      yprev  = yt;

      const float E = __expf(xe);

      // matvec: acc_j = sum_i p[i] * W[i][j], p broadcast from LDS
      float a0 = 0.f, a1 = 0.f, a2 = 0.f, a3 = 0.f;
#pragma unroll
      for (int q = 0; q < 16; ++q) {
        const float4 pv = reinterpret_cast<const float4*>(pbuf)[q];
        a0 = fmaf(pv.x, Wcol[4 * q + 0], a0);
        a1 = fmaf(pv.y, Wcol[4 * q + 1], a1);
        a2 = fmaf(pv.z, Wcol[4 * q + 2], a2);
        a3 = fmaf(pv.w, Wcol[4 * q + 3], a3);
      }
      float pn = ((a0 + a1) + (a2 + a3)) * E;

      // renormalize by wave-max every 8 steps (k==7) to stay in fp32 range
      if (k == 7) {
        float m = pn;
#pragma unroll
        for (int off = 32; off >= 1; off >>= 1)
          m = fmaxf(m, __shfl_xor(m, off, 64));
        pn *= 1.0f / m;
        logacc += __logf(m);
      }

      pbuf[j] = pn;   // in-wave LDS ordering keeps this after the reads above
      p = pn;
    }

    if (more) {
#pragma unroll
      for (int k = 0; k < 8; ++k) {
        xb[k] = xn[k];
        yb[k] = yn[k];
      }
    }
  }

  // ---- epilogue: reductions + output ----
  float esum = emit;
#pragma unroll
  for (int off = 32; off >= 1; off >>= 1) esum += __shfl_xor(esum, off, 64);

  float psum = p;
#pragma unroll
  for (int off = 32; off >= 1; off >>= 1) psum += __shfl_xor(psum, off, 64);

  const float logz = logacc + __logf(psum);

  if (j == 0) out[b] = logz - (esum + trans);
}

}  // namespace

extern "C" void kernel_launch(void* const* d_in, const int* in_sizes, int n_in,
                              void* d_out, int out_size, void* d_ws, size_t ws_size,
                              hipStream_t stream) {
  const float* x  = (const float*)d_in[0];
  const float* U  = (const float*)d_in[1];
  const float* bs = (const float*)d_in[2];
  const float* be = (const float*)d_in[3];
  const int*   y  = (const int*)d_in[4];
  float* out = (float*)d_out;

  crf_fwd<<<kB, 64, 0, stream>>>(x, U, bs, be, y, out);
}

// Round 5
// 208.825 us; speedup vs baseline: 1.7683x; 1.7683x over previous
//
#include <hip/hip_runtime.h>

namespace {

constexpr int kB = 256;
constexpr int kT = 1024;
constexpr int kC = 64;

typedef _Float16 half1_t;
typedef _Float16 half2_t __attribute__((ext_vector_type(2)));

#if __has_builtin(__builtin_amdgcn_fdot2)
#define HAVE_FDOT2 1
#else
#define HAVE_FDOT2 0
#endif

__device__ __forceinline__ float dot2f(half2_t a, half2_t b, float c) {
#if HAVE_FDOT2
  return __builtin_amdgcn_fdot2(a, b, c, false);
#else
  return c + (float)a.x * (float)b.x + (float)a.y * (float)b.y;
#endif
}

__device__ __forceinline__ half2_t as_h2(unsigned int u) {
  return __builtin_bit_cast(half2_t, u);
}

// One wave per chain. lane = class j. Linear-domain recursion with f16 p in
// LDS, f16-packed W in registers, per-step exact power-of-2 renormalization
// via lane-0 exponent (SALU). Path energy computed in a t-parallel prepass.
__global__ __launch_bounds__(64, 1) void crf_fwd(
    const float* __restrict__ x,    // [B,T,C]
    const float* __restrict__ U,    // [C,C]
    const float* __restrict__ bs,   // [C]
    const float* __restrict__ be,   // [C]
    const int*   __restrict__ y,    // [B,T]
    float*       __restrict__ out)  // [B,1]
{
  const int b = blockIdx.x;
  const int j = threadIdx.x & 63;

  __shared__ __align__(16) half1_t pbuf[kC];

  const float* xbase = x + (size_t)b * kT * kC;     // x[b][t][c]
  const float* xcol  = xbase + j;                   // lane's class column
  const int*   yrow  = y + (size_t)b * kT;

  // ---- prepass: path energy, t-parallel (lane handles 16 timesteps) ----
  float pe = 0.f;
  {
    const int t0 = j * 16;
    int yv[17];
#pragma unroll
    for (int k = 0; k < 16; ++k) yv[k + 1] = yrow[t0 + k];
    yv[0] = (j > 0) ? yrow[t0 - 1] : 0;
#pragma unroll
    for (int k = 0; k < 16; ++k) {
      const int t = t0 + k;
      pe += xbase[(size_t)t * kC + yv[k + 1]];          // emission
      if (t >= 1) pe += U[yv[k] * kC + yv[k + 1]];      // transition
    }
    if (j == 0)  pe += bs[yv[1]];    // boundary on y[0]
    if (j == 63) pe += be[yv[16]];   // boundary on y[T-1]
#pragma unroll
    for (int off = 32; off >= 1; off >>= 1) pe += __shfl_xor(pe, off, 64);
  }

  // ---- W column for this lane, packed f16 pairs: Wp[w]=(W[2w][j],W[2w+1][j])
  half2_t Wp[32];
#pragma unroll
  for (int w = 0; w < 32; ++w) {
    half2_t hw;
    hw.x = (half1_t)__expf(U[(2 * w + 0) * kC + j]);
    hw.y = (half1_t)__expf(U[(2 * w + 1) * kC + j]);
    Wp[w] = hw;
  }

  const float bsj = bs[j];
  const float bej = be[j];

  // ---- t=0 init ----
  float xb[8];
#pragma unroll
  for (int k = 0; k < 8; ++k) xb[k] = xcol[k * kC];

  int   sacc;   // uniform: sum of power-of-2 renorm exponents
  float pl;     // this lane's stored (scaled) p value
  {
    const float p0 = __expf(xb[0] + bsj);
    const int e0 = (__builtin_amdgcn_readfirstlane(__float_as_uint(p0)) >> 23) & 255;
    sacc = e0 - 127;
    const float scale = __uint_as_float((unsigned)(254 - e0) << 23);
    pl = p0 * scale;                 // lane0 ~ 1.0
    pbuf[j] = (half1_t)pl;
  }

  // ---- main loop: 128 groups of 8 steps ----
  for (int g = 0; g < 128; ++g) {
    float xn[8];
    if (g < 127) {
#pragma unroll
      for (int k = 0; k < 8; ++k) xn[k] = xcol[((g + 1) * 8 + k) * kC];
    }

    // E for this group — off the p critical path
    float Eb[8];
#pragma unroll
    for (int k = 0; k < 8; ++k) {
      float xe = xb[k];
      if (g == 127 && k == 7) xe += bej;   // t == T-1 boundary
      Eb[k] = __expf(xe);
    }

#pragma unroll
    for (int k = 0; k < 8; ++k) {
      if (g == 0 && k == 0) continue;      // t=0 done in init

      // broadcast-read whole p vector (64 f16 = 8 x b128, uniform address)
      const uint4* sh = reinterpret_cast<const uint4*>(pbuf);
      float acc[8];
#pragma unroll
      for (int q = 0; q < 8; ++q) {
        const uint4 v = sh[q];
        float a;
        a = dot2f(as_h2(v.x), Wp[4 * q + 0], 0.f);
        a = dot2f(as_h2(v.y), Wp[4 * q + 1], a);
        a = dot2f(as_h2(v.z), Wp[4 * q + 2], a);
        a = dot2f(as_h2(v.w), Wp[4 * q + 3], a);
        acc[q] = a;
      }
      const float s01 = acc[0] + acc[1], s23 = acc[2] + acc[3];
      const float s45 = acc[4] + acc[5], s67 = acc[6] + acc[7];
      const float ssum = (s01 + s23) + (s45 + s67);

      float pn = ssum * Eb[k];

      // exact pow2 renorm, uniform scale from lane 0's exponent (SALU path)
      const int e0 = (__builtin_amdgcn_readfirstlane(__float_as_uint(pn)) >> 23) & 255;
      sacc += e0 - 127;
      const float scale = __uint_as_float((unsigned)(254 - e0) << 23);
      pl = pn * scale;
      pbuf[j] = (half1_t)pl;
    }

    if (g < 127) {
#pragma unroll
      for (int k = 0; k < 8; ++k) xb[k] = xn[k];
    }
  }

  // ---- epilogue ----
  float psum = pl;
#pragma unroll
  for (int off = 32; off >= 1; off >>= 1) psum += __shfl_xor(psum, off, 64);

  const float logz = (float)sacc * 0.69314718055994531f + __logf(psum);

  if (j == 0) out[b] = logz - pe;
}

}  // namespace

extern "C" void kernel_launch(void* const* d_in, const int* in_sizes, int n_in,
                              void* d_out, int out_size, void* d_ws, size_t ws_size,
                              hipStream_t stream) {
  const float* x  = (const float*)d_in[0];
  const float* U  = (const float*)d_in[1];
  const float* bs = (const float*)d_in[2];
  const float* be = (const float*)d_in[3];
  const int*   y  = (const int*)d_in[4];
  float* out = (float*)d_out;

  crf_fwd<<<kB, 64, 0, stream>>>(x, U, bs, be, y, out);
}